// Round 2
// baseline (109.782 us; speedup 1.0000x reference)
//
#include <hip/hip_runtime.h>

#if defined(__has_builtin)
#  if __has_builtin(__builtin_amdgcn_exp2f)
#    define EXP2F(x) __builtin_amdgcn_exp2f(x)
#  else
#    define EXP2F(x) exp2f(x)
#  endif
#else
#  define EXP2F(x) exp2f(x)
#endif

constexpr int NPIX  = 262144;
constexpr int NC    = 1024;
constexpr int NG    = 256;
constexpr int BLOCK = 256;
constexpr int PIX_PER_BLOCK = BLOCK * 2;   // 512 (2 pixel-groups per thread)

// pack centers as (cx, cy, alpha * 2^{f*|c|^2}, 0) so the main loop is
// mul + fma + exp + fmac per center, each with <=1 SGPR operand.
__global__ void prep_centers(const float* __restrict__ alphas,
                             const float* __restrict__ centers,
                             const float* __restrict__ sdp2p,
                             float4* __restrict__ cpack)
{
    const int c = blockIdx.x * blockDim.x + threadIdx.x;
    if (c < NC) {
        const float f  = -1.44269504088896340736f / (2.0f * sdp2p[0]);
        const float cx = centers[2 * c + 0];
        const float cy = centers[2 * c + 1];
        cpack[c] = make_float4(cx, cy, alphas[c] * EXP2F(f * (cx * cx + cy * cy)), 0.f);
    }
}

__global__ __launch_bounds__(BLOCK, 2)
void kbpa_main(const float* __restrict__ betas,
               const float* __restrict__ K,
               const float* __restrict__ pixels,
               const float* __restrict__ sdp2p,
               const float4* __restrict__ cpack,
               float* __restrict__ out)
{
    const int tid  = threadIdx.x;
    const int lane = tid & 63;
    const int wave = tid >> 6;
    const int l4   = lane & 15;        // column-slot within a row's 16-lane team
    const int lg   = lane >> 4;        // row sub-index within a 4-row iteration
    const int own  = l4 * 4 + lg;      // owned row within this wave's 64-row group

    const float f   = -1.44269504088896340736f / (2.0f * sdp2p[0]);
    const float m2f = -2.0f * f;

    // betas fragments: this lane covers cols c0 = l4*4 + k*64 .. +3, k=0..3
    // betas row-major (256,2): bf4[i] = {b[2i].x, b[2i].y, b[2i+1].x, b[2i+1].y}
    const float4* bf4 = (const float4*)betas;
    float4 b0[4], b1[4];
    #pragma unroll
    for (int k = 0; k < 4; ++k) {
        b0[k] = bf4[l4 * 2 + k * 32];
        b1[k] = bf4[l4 * 2 + k * 32 + 1];
    }

    const int blockBase = blockIdx.x * PIX_PER_BLOCK;
    const int g0 = blockBase + wave * 64;          // rows of group 0
    const int g1 = g0 + BLOCK;                     // rows of group 1

    const float2* pix2 = (const float2*)pixels;
    const float2 pixA = pix2[g0 + own];
    const float2 pixB = pix2[g1 + own];

    // ---------------- phase 1: stage A for group 0 ----------------
    float dxA = 0.f, dyA = 0.f;
    #pragma unroll 2
    for (int it = 0; it < 16; ++it) {
        const int row = g0 + it * 4 + lg;
        const float4* kr = (const float4*)(K + (size_t)row * NG);
        const float4 kv0 = kr[l4];
        const float4 kv1 = kr[l4 + 16];
        const float4 kv2 = kr[l4 + 32];
        const float4 kv3 = kr[l4 + 48];
        float sx, sy;
        sx = kv0.x * b0[0].x + kv0.y * b0[0].z;
        sy = kv0.x * b0[0].y + kv0.y * b0[0].w;
        sx = fmaf(kv0.z, b1[0].x, sx); sy = fmaf(kv0.z, b1[0].y, sy);
        sx = fmaf(kv0.w, b1[0].z, sx); sy = fmaf(kv0.w, b1[0].w, sy);
        sx = fmaf(kv1.x, b0[1].x, sx); sy = fmaf(kv1.x, b0[1].y, sy);
        sx = fmaf(kv1.y, b0[1].z, sx); sy = fmaf(kv1.y, b0[1].w, sy);
        sx = fmaf(kv1.z, b1[1].x, sx); sy = fmaf(kv1.z, b1[1].y, sy);
        sx = fmaf(kv1.w, b1[1].z, sx); sy = fmaf(kv1.w, b1[1].w, sy);
        sx = fmaf(kv2.x, b0[2].x, sx); sy = fmaf(kv2.x, b0[2].y, sy);
        sx = fmaf(kv2.y, b0[2].z, sx); sy = fmaf(kv2.y, b0[2].w, sy);
        sx = fmaf(kv2.z, b1[2].x, sx); sy = fmaf(kv2.z, b1[2].y, sy);
        sx = fmaf(kv2.w, b1[2].z, sx); sy = fmaf(kv2.w, b1[2].w, sy);
        sx = fmaf(kv3.x, b0[3].x, sx); sy = fmaf(kv3.x, b0[3].y, sy);
        sx = fmaf(kv3.y, b0[3].z, sx); sy = fmaf(kv3.y, b0[3].w, sy);
        sx = fmaf(kv3.z, b1[3].x, sx); sy = fmaf(kv3.z, b1[3].y, sy);
        sx = fmaf(kv3.w, b1[3].z, sx); sy = fmaf(kv3.w, b1[3].w, sy);
        #pragma unroll
        for (int m = 1; m < 16; m <<= 1) {
            sx += __shfl_xor(sx, m);
            sy += __shfl_xor(sy, m);
        }
        if (l4 == it) { dxA = pixA.x - sx; dyA = pixA.y - sy; }
    }

    const float dxsA = m2f * dxA;
    const float dysA = m2f * dyA;
    const float pnA  = f * (dxA * dxA + dyA * dyA);

    // ------- phase 2: stage A for group 1 interleaved with centers for A -------
    float accA = 0.f;
    float dxB = 0.f, dyB = 0.f;
    for (int it = 0; it < 16; ++it) {
        const int row = g1 + it * 4 + lg;
        const float4* kr = (const float4*)(K + (size_t)row * NG);
        const float4 kv0 = kr[l4];
        const float4 kv1 = kr[l4 + 16];
        const float4 kv2 = kr[l4 + 32];
        const float4 kv3 = kr[l4 + 48];

        // 64 centers for pixel A while the K loads are in flight
        const int cbase = it * 64;
        #pragma unroll 8
        for (int c = cbase; c < cbase + 64; ++c) {
            const float4 cp = cpack[c];
            accA = fmaf(cp.z, EXP2F(fmaf(dxsA, cp.x, dysA * cp.y)), accA);
        }

        float sx, sy;
        sx = kv0.x * b0[0].x + kv0.y * b0[0].z;
        sy = kv0.x * b0[0].y + kv0.y * b0[0].w;
        sx = fmaf(kv0.z, b1[0].x, sx); sy = fmaf(kv0.z, b1[0].y, sy);
        sx = fmaf(kv0.w, b1[0].z, sx); sy = fmaf(kv0.w, b1[0].w, sy);
        sx = fmaf(kv1.x, b0[1].x, sx); sy = fmaf(kv1.x, b0[1].y, sy);
        sx = fmaf(kv1.y, b0[1].z, sx); sy = fmaf(kv1.y, b0[1].w, sy);
        sx = fmaf(kv1.z, b1[1].x, sx); sy = fmaf(kv1.z, b1[1].y, sy);
        sx = fmaf(kv1.w, b1[1].z, sx); sy = fmaf(kv1.w, b1[1].w, sy);
        sx = fmaf(kv2.x, b0[2].x, sx); sy = fmaf(kv2.x, b0[2].y, sy);
        sx = fmaf(kv2.y, b0[2].z, sx); sy = fmaf(kv2.y, b0[2].w, sy);
        sx = fmaf(kv2.z, b1[2].x, sx); sy = fmaf(kv2.z, b1[2].y, sy);
        sx = fmaf(kv2.w, b1[2].z, sx); sy = fmaf(kv2.w, b1[2].w, sy);
        sx = fmaf(kv3.x, b0[3].x, sx); sy = fmaf(kv3.x, b0[3].y, sy);
        sx = fmaf(kv3.y, b0[3].z, sx); sy = fmaf(kv3.y, b0[3].w, sy);
        sx = fmaf(kv3.z, b1[3].x, sx); sy = fmaf(kv3.z, b1[3].y, sy);
        sx = fmaf(kv3.w, b1[3].z, sx); sy = fmaf(kv3.w, b1[3].w, sy);
        #pragma unroll
        for (int m = 1; m < 16; m <<= 1) {
            sx += __shfl_xor(sx, m);
            sy += __shfl_xor(sy, m);
        }
        if (l4 == it) { dxB = pixB.x - sx; dyB = pixB.y - sy; }
    }
    out[g0 + own] = accA * EXP2F(pnA);

    // ---------------- phase 3: centers for pixel B ----------------
    const float dxsB = m2f * dxB;
    const float dysB = m2f * dyB;
    const float pnB  = f * (dxB * dxB + dyB * dyB);
    float accB = 0.f;
    #pragma unroll 8
    for (int c = 0; c < NC; ++c) {
        const float4 cp = cpack[c];
        accB = fmaf(cp.z, EXP2F(fmaf(dxsB, cp.x, dysB * cp.y)), accB);
    }
    out[g1 + own] = accB * EXP2F(pnB);
}

extern "C" void kernel_launch(void* const* d_in, const int* in_sizes, int n_in,
                              void* d_out, int out_size, void* d_ws, size_t ws_size,
                              hipStream_t stream)
{
    const float* alphas  = (const float*)d_in[0];
    const float* betas   = (const float*)d_in[1];
    const float* K       = (const float*)d_in[2];
    const float* pixels  = (const float*)d_in[3];
    const float* centers = (const float*)d_in[4];
    const float* sdp2    = (const float*)d_in[5];
    float* outp          = (float*)d_out;
    float4* cpack        = (float4*)d_ws;

    hipLaunchKernelGGL(prep_centers, dim3((NC + 255) / 256), dim3(256), 0, stream,
                       alphas, centers, sdp2, cpack);
    hipLaunchKernelGGL(kbpa_main, dim3(NPIX / PIX_PER_BLOCK), dim3(BLOCK), 0, stream,
                       betas, K, pixels, sdp2, cpack, outp);
}

// Round 4
// 85.023 us; speedup vs baseline: 1.2912x; 1.2912x over previous
//
#include <hip/hip_runtime.h>

#if defined(__has_builtin)
#  if __has_builtin(__builtin_amdgcn_exp2f)
#    define EXP2F(x) __builtin_amdgcn_exp2f(x)
#  else
#    define EXP2F(x) exp2f(x)
#  endif
#else
#  define EXP2F(x) exp2f(x)
#endif

constexpr int NPIX  = 262144;
constexpr int NC    = 1024;
constexpr int NG    = 256;
constexpr int BLOCK = 256;
constexpr int PIX_PER_BLOCK = BLOCK * 2;   // 512: 2 pixels per thread, one stage-B pass

// 16-lane butterfly sum on the VALU pipe (DPP) — zero ds ops, keeps lgkmcnt clean.
template <int CTRL>
__device__ __forceinline__ float dpp_add(float v) {
    union { float f; int i; } u, t;
    u.f = v;
    t.i = __builtin_amdgcn_update_dpp(0, u.i, CTRL, 0xF, 0xF, true);
    return v + t.f;
}
__device__ __forceinline__ float sum16(float v) {
    v = dpp_add<0xB1>(v);   // quad_perm [1,0,3,2]  == xor 1
    v = dpp_add<0x4E>(v);   // quad_perm [2,3,0,1]  == xor 2
    v = dpp_add<0x141>(v);  // row_half_mirror      == xor 4 for sums
    v = dpp_add<0x140>(v);  // row_mirror           == xor 8 for sums
    return v;               // all 16 lanes hold the group total
}

__global__ __launch_bounds__(BLOCK, 2)
void kbpa_fused(const float* __restrict__ alphas,
                const float* __restrict__ betas,
                const float* __restrict__ K,
                const float* __restrict__ pixels,
                const float* __restrict__ centers,
                const float* __restrict__ sdp2p,
                float* __restrict__ out)
{
    __shared__ float4 cpack[NC];       // (cx, cy, alpha*2^{f|c|^2}, 0) — 16 KB

    const int tid  = threadIdx.x;
    const int lane = tid & 63;
    const int wave = tid >> 6;
    const int l4   = lane & 15;        // column-slot within a row's 16-lane team
    const int lg   = lane >> 4;        // row sub-index within a 4-row iteration
    const int own  = l4 * 4 + lg;      // owned row within this wave's 64-row group

    const float f   = -1.44269504088896340736f / (2.0f * sdp2p[0]);
    const float m2f = -2.0f * f;

    // pack centers into LDS (fold 2^{f|c|^2} into alpha)
    for (int c = tid; c < NC; c += BLOCK) {
        const float cx = centers[2 * c + 0];
        const float cy = centers[2 * c + 1];
        cpack[c] = make_float4(cx, cy, alphas[c] * EXP2F(f * (cx * cx + cy * cy)), 0.f);
    }

    // betas fragments: lane covers cols 4*l4..+3 of each 64-col quarter
    const float4* bf4 = (const float4*)betas;
    float4 b0[4], b1[4];
    #pragma unroll
    for (int k = 0; k < 4; ++k) {
        b0[k] = bf4[l4 * 2 + k * 32];
        b1[k] = bf4[l4 * 2 + k * 32 + 1];
    }

    const int blockBase = blockIdx.x * PIX_PER_BLOCK;
    const int g0 = blockBase + wave * 64;
    const int g1 = g0 + BLOCK;

    const float2* pix2 = (const float2*)pixels;
    const float2 pixA = pix2[g0 + own];
    const float2 pixB = pix2[g1 + own];

    // ---- stage A: wave-cooperative deformed coords, DPP reduction ----
    float dxA = 0.f, dyA = 0.f, dxB = 0.f, dyB = 0.f;
    #pragma unroll 2
    for (int it = 0; it < 16; ++it) {
        const float4* kr = (const float4*)(K + (size_t)(g0 + it * 4 + lg) * NG);
        float4 kv[4];
        #pragma unroll
        for (int k = 0; k < 4; ++k) kv[k] = kr[l4 + 16 * k];
        float sx = 0.f, sy = 0.f;
        #pragma unroll
        for (int k = 0; k < 4; ++k) {
            sx = fmaf(kv[k].x, b0[k].x, sx); sy = fmaf(kv[k].x, b0[k].y, sy);
            sx = fmaf(kv[k].y, b0[k].z, sx); sy = fmaf(kv[k].y, b0[k].w, sy);
            sx = fmaf(kv[k].z, b1[k].x, sx); sy = fmaf(kv[k].z, b1[k].y, sy);
            sx = fmaf(kv[k].w, b1[k].z, sx); sy = fmaf(kv[k].w, b1[k].w, sy);
        }
        sx = sum16(sx); sy = sum16(sy);
        if (l4 == it) { dxA = pixA.x - sx; dyA = pixA.y - sy; }
    }
    #pragma unroll 2
    for (int it = 0; it < 16; ++it) {
        const float4* kr = (const float4*)(K + (size_t)(g1 + it * 4 + lg) * NG);
        float4 kv[4];
        #pragma unroll
        for (int k = 0; k < 4; ++k) kv[k] = kr[l4 + 16 * k];
        float sx = 0.f, sy = 0.f;
        #pragma unroll
        for (int k = 0; k < 4; ++k) {
            sx = fmaf(kv[k].x, b0[k].x, sx); sy = fmaf(kv[k].x, b0[k].y, sy);
            sx = fmaf(kv[k].y, b0[k].z, sx); sy = fmaf(kv[k].y, b0[k].w, sy);
            sx = fmaf(kv[k].z, b1[k].x, sx); sy = fmaf(kv[k].z, b1[k].y, sy);
            sx = fmaf(kv[k].w, b1[k].z, sx); sy = fmaf(kv[k].w, b1[k].w, sy);
        }
        sx = sum16(sx); sy = sum16(sy);
        if (l4 == it) { dxB = pixB.x - sx; dyB = pixB.y - sy; }
    }

    __syncthreads();   // cpack ready (all waves arrive together after stage A)

    // ---- stage B: one pass over 1024 centers, both pixels per read ----
    const float dxs0 = m2f * dxA, dys0 = m2f * dyA;
    const float dxs1 = m2f * dxB, dys1 = m2f * dyB;
    const float pn0  = f * (dxA * dxA + dyA * dyA);
    const float pn1  = f * (dxB * dxB + dyB * dyB);
    float acc0 = 0.f, acc1 = 0.f;
    #pragma unroll 8
    for (int c = 0; c < NC; ++c) {
        const float4 cp = cpack[c];
        const float e0 = EXP2F(fmaf(dxs0, cp.x, dys0 * cp.y));
        const float e1 = EXP2F(fmaf(dxs1, cp.x, dys1 * cp.y));
        acc0 = fmaf(cp.z, e0, acc0);
        acc1 = fmaf(cp.z, e1, acc1);
    }
    out[g0 + own] = acc0 * EXP2F(pn0);
    out[g1 + own] = acc1 * EXP2F(pn1);
}

extern "C" void kernel_launch(void* const* d_in, const int* in_sizes, int n_in,
                              void* d_out, int out_size, void* d_ws, size_t ws_size,
                              hipStream_t stream)
{
    const float* alphas  = (const float*)d_in[0];
    const float* betas   = (const float*)d_in[1];
    const float* K       = (const float*)d_in[2];
    const float* pixels  = (const float*)d_in[3];
    const float* centers = (const float*)d_in[4];
    const float* sdp2    = (const float*)d_in[5];
    float* outp          = (float*)d_out;

    hipLaunchKernelGGL(kbpa_fused, dim3(NPIX / PIX_PER_BLOCK), dim3(BLOCK), 0, stream,
                       alphas, betas, K, pixels, centers, sdp2, outp);
}

// Round 5
// 80.037 us; speedup vs baseline: 1.3716x; 1.0623x over previous
//
#include <hip/hip_runtime.h>

#if defined(__has_builtin)
#  if __has_builtin(__builtin_amdgcn_exp2f)
#    define EXP2F(x) __builtin_amdgcn_exp2f(x)
#  else
#    define EXP2F(x) exp2f(x)
#  endif
#else
#  define EXP2F(x) exp2f(x)
#endif

constexpr int NPIX  = 262144;
constexpr int NC    = 1024;
constexpr int NG    = 256;
constexpr int BLOCK = 256;
constexpr int PIX_PER_BLOCK = BLOCK * 2;   // 512: 2 groups of 64 rows per wave

// ---- 16-lane butterfly sum on the VALU pipe (DPP), zero ds ops ----
template <int CTRL>
__device__ __forceinline__ float dpp_add(float v) {
    union { float f; int i; } u, t;
    u.f = v;
    t.i = __builtin_amdgcn_update_dpp(0, u.i, CTRL, 0xF, 0xF, true);
    return v + t.f;
}
__device__ __forceinline__ float sum16(float v) {
    v = dpp_add<0xB1>(v);   // quad_perm xor1
    v = dpp_add<0x4E>(v);   // quad_perm xor2
    v = dpp_add<0x141>(v);  // row_half_mirror (xor4 for sums)
    v = dpp_add<0x140>(v);  // row_mirror      (xor8 for sums)
    return v;               // all 16 lanes hold the group total
}

// prep: SoA arrays in d_ws: cx[NC] | cy[NC] | ca[NC]  (ca = alpha * 2^{f|c|^2})
__global__ void prep_centers(const float* __restrict__ alphas,
                             const float* __restrict__ centers,
                             const float* __restrict__ sdp2p,
                             float* __restrict__ ws)
{
    const int c = blockIdx.x * blockDim.x + threadIdx.x;
    if (c < NC) {
        const float f  = -1.44269504088896340736f / (2.0f * sdp2p[0]);
        const float cx = centers[2 * c + 0];
        const float cy = centers[2 * c + 1];
        ws[c]          = cx;
        ws[NC + c]     = cy;
        ws[2 * NC + c] = alphas[c] * EXP2F(f * (cx * cx + cy * cy));
    }
}

// systolic centers pass: state (dxs,dys,acc) ring-rotates over 64 lanes,
// each lane applies its 16 register-resident centers per visit.
__device__ __forceinline__ float systolic_b(float dx, float dy, float m2f,
                                            const float4 rcx[4], const float4 rcy[4],
                                            const float4 rca[4], int src)
{
    float dxs = m2f * dx, dys = m2f * dy, acc = 0.f;
    for (int t = 0; t < 64; ++t) {
        #pragma unroll
        for (int jj = 0; jj < 4; ++jj) {
            acc = fmaf(rca[jj].x, EXP2F(fmaf(dxs, rcx[jj].x, dys * rcy[jj].x)), acc);
            acc = fmaf(rca[jj].y, EXP2F(fmaf(dxs, rcx[jj].y, dys * rcy[jj].y)), acc);
            acc = fmaf(rca[jj].z, EXP2F(fmaf(dxs, rcx[jj].z, dys * rcy[jj].z)), acc);
            acc = fmaf(rca[jj].w, EXP2F(fmaf(dxs, rcx[jj].w, dys * rcy[jj].w)), acc);
        }
        dxs = __shfl(dxs, src);
        dys = __shfl(dys, src);
        acc = __shfl(acc, src);
    }
    return acc;   // 64 rotations -> state (and acc) back at home lane
}

__global__ __launch_bounds__(BLOCK, 2)
void kbpa_main(const float* __restrict__ betas,
               const float* __restrict__ K,
               const float* __restrict__ pixels,
               const float* __restrict__ sdp2p,
               const float* __restrict__ ws,
               float* __restrict__ out)
{
    const int tid  = threadIdx.x;
    const int lane = tid & 63;
    const int wave = tid >> 6;
    const int l4   = lane & 15;
    const int lg   = lane >> 4;
    const int own  = l4 * 4 + lg;
    const int src  = (lane + 1) & 63;

    const float f   = -1.44269504088896340736f / (2.0f * sdp2p[0]);
    const float m2f = -2.0f * f;

    // resident centers: lane holds c = lane*16 .. lane*16+15 (SoA float4 loads)
    const float4* wcx4 = (const float4*)(ws);
    const float4* wcy4 = (const float4*)(ws + NC);
    const float4* wca4 = (const float4*)(ws + 2 * NC);
    float4 rcx[4], rcy[4], rca[4];
    #pragma unroll
    for (int jj = 0; jj < 4; ++jj) {
        rcx[jj] = wcx4[lane * 4 + jj];
        rcy[jj] = wcy4[lane * 4 + jj];
        rca[jj] = wca4[lane * 4 + jj];
    }

    // betas fragments (identical to round-4 stage A)
    const float4* bf4 = (const float4*)betas;
    float4 b0[4], b1[4];
    #pragma unroll
    for (int k = 0; k < 4; ++k) {
        b0[k] = bf4[l4 * 2 + k * 32];
        b1[k] = bf4[l4 * 2 + k * 32 + 1];
    }

    const int blockBase = blockIdx.x * PIX_PER_BLOCK;
    const int g0 = blockBase + wave * 64;
    const int g1 = g0 + BLOCK;

    const float2* pix2 = (const float2*)pixels;
    const float2 pixA = pix2[g0 + own];
    const float2 pixB = pix2[g1 + own];

    // ---- stage A for group 0 ----
    float dx0 = 0.f, dy0 = 0.f, dx1 = 0.f, dy1 = 0.f;
    #pragma unroll 2
    for (int it = 0; it < 16; ++it) {
        const float4* kr = (const float4*)(K + (size_t)(g0 + it * 4 + lg) * NG);
        float4 kv[4];
        #pragma unroll
        for (int k = 0; k < 4; ++k) kv[k] = kr[l4 + 16 * k];
        float sx = 0.f, sy = 0.f;
        #pragma unroll
        for (int k = 0; k < 4; ++k) {
            sx = fmaf(kv[k].x, b0[k].x, sx); sy = fmaf(kv[k].x, b0[k].y, sy);
            sx = fmaf(kv[k].y, b0[k].z, sx); sy = fmaf(kv[k].y, b0[k].w, sy);
            sx = fmaf(kv[k].z, b1[k].x, sx); sy = fmaf(kv[k].z, b1[k].y, sy);
            sx = fmaf(kv[k].w, b1[k].z, sx); sy = fmaf(kv[k].w, b1[k].w, sy);
        }
        sx = sum16(sx); sy = sum16(sy);
        if (l4 == it) { dx0 = pixA.x - sx; dy0 = pixA.y - sy; }
    }

    // wave-parity schedule: even waves compute B(g0) now (overlaps odd waves'
    // K streaming); odd waves keep streaming and compute both B passes later.
    const bool early = (wave & 1) == 0;
    float r0 = 0.f;
    if (early) r0 = systolic_b(dx0, dy0, m2f, rcx, rcy, rca, src);

    // ---- stage A for group 1 ----
    #pragma unroll 2
    for (int it = 0; it < 16; ++it) {
        const float4* kr = (const float4*)(K + (size_t)(g1 + it * 4 + lg) * NG);
        float4 kv[4];
        #pragma unroll
        for (int k = 0; k < 4; ++k) kv[k] = kr[l4 + 16 * k];
        float sx = 0.f, sy = 0.f;
        #pragma unroll
        for (int k = 0; k < 4; ++k) {
            sx = fmaf(kv[k].x, b0[k].x, sx); sy = fmaf(kv[k].x, b0[k].y, sy);
            sx = fmaf(kv[k].y, b0[k].z, sx); sy = fmaf(kv[k].y, b0[k].w, sy);
            sx = fmaf(kv[k].z, b1[k].x, sx); sy = fmaf(kv[k].z, b1[k].y, sy);
            sx = fmaf(kv[k].w, b1[k].z, sx); sy = fmaf(kv[k].w, b1[k].w, sy);
        }
        sx = sum16(sx); sy = sum16(sy);
        if (l4 == it) { dx1 = pixB.x - sx; dy1 = pixB.y - sy; }
    }

    if (!early) r0 = systolic_b(dx0, dy0, m2f, rcx, rcy, rca, src);
    const float r1 = systolic_b(dx1, dy1, m2f, rcx, rcy, rca, src);

    out[g0 + own] = r0 * EXP2F(f * (dx0 * dx0 + dy0 * dy0));
    out[g1 + own] = r1 * EXP2F(f * (dx1 * dx1 + dy1 * dy1));
}

extern "C" void kernel_launch(void* const* d_in, const int* in_sizes, int n_in,
                              void* d_out, int out_size, void* d_ws, size_t ws_size,
                              hipStream_t stream)
{
    const float* alphas  = (const float*)d_in[0];
    const float* betas   = (const float*)d_in[1];
    const float* K       = (const float*)d_in[2];
    const float* pixels  = (const float*)d_in[3];
    const float* centers = (const float*)d_in[4];
    const float* sdp2    = (const float*)d_in[5];
    float* outp          = (float*)d_out;
    float* ws            = (float*)d_ws;

    hipLaunchKernelGGL(prep_centers, dim3(NC / 256), dim3(256), 0, stream,
                       alphas, centers, sdp2, ws);
    hipLaunchKernelGGL(kbpa_main, dim3(NPIX / PIX_PER_BLOCK), dim3(BLOCK), 0, stream,
                       betas, K, pixels, sdp2, ws, outp);
}